// Round 12
// baseline (362.501 us; speedup 1.0000x reference)
//
#include <hip/hip_runtime.h>
#include <hip/hip_bf16.h>
#include <math.h>

#define TPB 256
constexpr int Bb = 8, Mm = 2048, Nn = 8192, HID = 128;
constexpr int KNNB = Bb * 128;                // 1024 knn blocks

typedef __attribute__((ext_vector_type(8))) short short8;
typedef __attribute__((ext_vector_type(4))) float f32x4;

__device__ __forceinline__ unsigned short f2b(float x) {
  __hip_bfloat16 h = __float2bfloat16(x);
  return *reinterpret_cast<unsigned short*>(&h);
}

// in-place: a = sorted-asc top-8 of union(a,b)
__device__ __forceinline__ void mergeTop8(float a[8], const float b[8]) {
  float w[8];
  #pragma unroll
  for (int i = 0; i < 8; ++i) w[i] = fmaxf(a[i], b[7 - i]);
  #pragma unroll
  for (int i = 0; i < 4; ++i) {
    float lo = fminf(w[i], w[i + 4]); w[i + 4] = fmaxf(w[i], w[i + 4]); w[i] = lo;
  }
  #pragma unroll
  for (int g = 0; g < 8; g += 4)
    #pragma unroll
    for (int i = 0; i < 2; ++i) {
      float lo = fminf(w[g + i], w[g + i + 2]);
      w[g + i + 2] = fmaxf(w[g + i], w[g + i + 2]); w[g + i] = lo;
    }
  #pragma unroll
  for (int i = 0; i < 8; i += 2) {
    float lo = fminf(w[i], w[i + 1]); w[i + 1] = fmaxf(w[i], w[i + 1]); w[i] = lo;
  }
  #pragma unroll
  for (int i = 0; i < 8; ++i) a[i] = w[i];
}
__device__ __forceinline__ float t8of(const float a[8], const float b[8]) {
  float t = fmaxf(a[0], b[7]);
  #pragma unroll
  for (int i = 1; i < 8; ++i) t = fminf(t, fmaxf(a[i], b[7 - i]));
  return t;
}

#define INSERT8(L, u)                                                          \
  {                                                                            \
    L[0] = __builtin_amdgcn_fmed3f(u, L[0], L[1]);                             \
    L[1] = __builtin_amdgcn_fmed3f(u, L[1], L[2]);                             \
    L[2] = __builtin_amdgcn_fmed3f(u, L[2], L[3]);                             \
    L[3] = __builtin_amdgcn_fmed3f(u, L[3], L[4]);                             \
    L[4] = __builtin_amdgcn_fmed3f(u, L[4], L[5]);                             \
    L[5] = __builtin_amdgcn_fmed3f(u, L[5], L[6]);                             \
    L[6] = __builtin_amdgcn_fmed3f(u, L[6], L[7]);                             \
    L[7] = fmaxf(L[7], u);                                                     \
  }

// knn phase core. Returns comb in cq[6] on writer lanes (s==k).
// If wrOut != nullptr, also writes comb rows to wrOut (fallback path).
__device__ __forceinline__ void knn_phase(const float* __restrict__ partial,
                                          const float* __restrict__ predicted,
                                          float4* pts, int b, int qt, int tid,
                                          float cq[6], float* wrOut) {
  const float* pb = partial + (size_t)b * Mm * 3;
  for (int i = tid; i < Mm; i += TPB) {
    float x = pb[3 * i], y = pb[3 * i + 1], z = pb[3 * i + 2];
    pts[i] = make_float4(x, y, z, -0.5f * fmaf(x, x, fmaf(y, y, z * z)));
  }
  __syncthreads();

  const int lane = tid & 63, w = tid >> 6;
  const int s = lane & 15, g = lane >> 4;
  const int qbase = qt * 64 + w * 16 + g * 4;
  const float4* qp = (const float4*)(predicted + ((size_t)b * Nn + qbase) * 3);
  const float4 qa = qp[0], qb4 = qp[1], qc = qp[2];
  const float q0x = qa.x,  q0y = qa.y,  q0z = qa.z;
  const float q1x = qa.w,  q1y = qb4.x, q1z = qb4.y;
  const float q2x = qb4.z, q2y = qb4.w, q2z = qc.x;
  const float q3x = qc.y,  q3y = qc.z,  q3z = qc.w;

  float l0[8], l1[8], l2[8], l3[8];
  #pragma unroll
  for (int i = 0; i < 8; ++i) { l0[i] = -INFINITY; l1[i] = -INFINITY;
                                l2[i] = -INFINITY; l3[i] = -INFINITY; }
  #pragma unroll 4
  for (int mm = 0; mm < 128; ++mm) {
    float4 p = pts[s + 16 * mm];
    float u0 = fmaf(q0x, p.x, fmaf(q0y, p.y, fmaf(q0z, p.z, p.w)));
    float u1 = fmaf(q1x, p.x, fmaf(q1y, p.y, fmaf(q1z, p.z, p.w)));
    float u2 = fmaf(q2x, p.x, fmaf(q2y, p.y, fmaf(q2z, p.z, p.w)));
    float u3 = fmaf(q3x, p.x, fmaf(q3y, p.y, fmaf(q3z, p.z, p.w)));
    INSERT8(l0, u0); INSERT8(l1, u1); INSERT8(l2, u2); INSERT8(l3, u3);
  }

  #pragma unroll
  for (int dd = 0; dd < 3; ++dd) {
    const int d = 1 << dd;
    float ob[8];
    #pragma unroll
    for (int i = 0; i < 8; ++i) ob[i] = __shfl_xor(l0[i], d);
    mergeTop8(l0, ob);
    #pragma unroll
    for (int i = 0; i < 8; ++i) ob[i] = __shfl_xor(l1[i], d);
    mergeTop8(l1, ob);
    #pragma unroll
    for (int i = 0; i < 8; ++i) ob[i] = __shfl_xor(l2[i], d);
    mergeTop8(l2, ob);
    #pragma unroll
    for (int i = 0; i < 8; ++i) ob[i] = __shfl_xor(l3[i], d);
    mergeTop8(l3, ob);
  }
  float t80, t81, t82, t83;
  {
    float ob[8];
    #pragma unroll
    for (int i = 0; i < 8; ++i) ob[i] = __shfl_xor(l0[i], 8);
    t80 = t8of(l0, ob);
    #pragma unroll
    for (int i = 0; i < 8; ++i) ob[i] = __shfl_xor(l1[i], 8);
    t81 = t8of(l1, ob);
    #pragma unroll
    for (int i = 0; i < 8; ++i) ob[i] = __shfl_xor(l2[i], 8);
    t82 = t8of(l2, ob);
    #pragma unroll
    for (int i = 0; i < 8; ++i) ob[i] = __shfl_xor(l3[i], 8);
    t83 = t8of(l3, ob);
  }

  float a0x = 0.f, a0y = 0.f, a0z = 0.f, c0 = 0.f;
  float a1x = 0.f, a1y = 0.f, a1z = 0.f, c1 = 0.f;
  float a2x = 0.f, a2y = 0.f, a2z = 0.f, c2 = 0.f;
  float a3x = 0.f, a3y = 0.f, a3z = 0.f, c3 = 0.f;
  #pragma unroll 4
  for (int mm = 0; mm < 128; ++mm) {
    float4 p = pts[s + 16 * mm];
    float u0 = fmaf(q0x, p.x, fmaf(q0y, p.y, fmaf(q0z, p.z, p.w)));  // bitwise
    float u1 = fmaf(q1x, p.x, fmaf(q1y, p.y, fmaf(q1z, p.z, p.w)));  //  same as
    float u2 = fmaf(q2x, p.x, fmaf(q2y, p.y, fmaf(q2z, p.z, p.w)));  //  pass A
    float u3 = fmaf(q3x, p.x, fmaf(q3y, p.y, fmaf(q3z, p.z, p.w)));
    float m0 = (u0 >= t80) ? 1.f : 0.f;
    float m1 = (u1 >= t81) ? 1.f : 0.f;
    float m2 = (u2 >= t82) ? 1.f : 0.f;
    float m3 = (u3 >= t83) ? 1.f : 0.f;
    a0x = fmaf(m0, p.x, a0x); a0y = fmaf(m0, p.y, a0y); a0z = fmaf(m0, p.z, a0z); c0 += m0;
    a1x = fmaf(m1, p.x, a1x); a1y = fmaf(m1, p.y, a1y); a1z = fmaf(m1, p.z, a1z); c1 += m1;
    a2x = fmaf(m2, p.x, a2x); a2y = fmaf(m2, p.y, a2y); a2z = fmaf(m2, p.z, a2z); c2 += m2;
    a3x = fmaf(m3, p.x, a3x); a3y = fmaf(m3, p.y, a3y); a3z = fmaf(m3, p.z, a3z); c3 += m3;
  }
  #pragma unroll
  for (int dd = 0; dd < 4; ++dd) {
    const int d = 1 << dd;
    a0x += __shfl_xor(a0x, d); a0y += __shfl_xor(a0y, d); a0z += __shfl_xor(a0z, d); c0 += __shfl_xor(c0, d);
    a1x += __shfl_xor(a1x, d); a1y += __shfl_xor(a1y, d); a1z += __shfl_xor(a1z, d); c1 += __shfl_xor(c1, d);
    a2x += __shfl_xor(a2x, d); a2y += __shfl_xor(a2y, d); a2z += __shfl_xor(a2z, d); c2 += __shfl_xor(c2, d);
    a3x += __shfl_xor(a3x, d); a3y += __shfl_xor(a3y, d); a3z += __shfl_xor(a3z, d); c3 += __shfl_xor(c3, d);
  }

  #pragma unroll
  for (int k = 0; k < 4; ++k) {
    if (s == k) {
      float qx = (k == 0) ? q0x : (k == 1) ? q1x : (k == 2) ? q2x : q3x;
      float qy = (k == 0) ? q0y : (k == 1) ? q1y : (k == 2) ? q2y : q3y;
      float qz = (k == 0) ? q0z : (k == 1) ? q1z : (k == 2) ? q2z : q3z;
      float t8 = (k == 0) ? t80 : (k == 1) ? t81 : (k == 2) ? t82 : t83;
      float sx = (k == 0) ? a0x : (k == 1) ? a1x : (k == 2) ? a2x : a3x;
      float sy = (k == 0) ? a0y : (k == 1) ? a1y : (k == 2) ? a2y : a3y;
      float sz = (k == 0) ? a0z : (k == 1) ? a1z : (k == 2) ? a2z : a3z;
      float cn = (k == 0) ? c0  : (k == 1) ? c1  : (k == 2) ? c2  : c3;
      if (cn != 8.0f) {                       // duplicate boundary ties: rare
        sx = sy = sz = 0.f; float cw = 0.f;
        for (int m = 0; m < Mm; ++m) {
          float4 p = pts[m];
          float u = fmaf(qx, p.x, fmaf(qy, p.y, fmaf(qz, p.z, p.w)));
          if (u > t8) { sx += p.x; sy += p.y; sz += p.z; cw += 1.f; }
        }
        int need = 8 - (int)cw, got = 0;
        for (int m = 0; m < Mm && got < need; ++m) {
          float4 p = pts[m];
          float u = fmaf(qx, p.x, fmaf(qy, p.y, fmaf(qz, p.z, p.w)));
          if (u == t8) { sx += p.x; sy += p.y; sz += p.z; ++got; }
        }
      }
      cq[0] = qx; cq[1] = qy; cq[2] = qz;
      cq[3] = sx * 0.125f; cq[4] = sy * 0.125f; cq[5] = sz * 0.125f;
      if (wrOut) {
        float2* co = (float2*)(wrOut + ((size_t)b * Nn + qbase + k) * 6);
        co[0] = make_float2(cq[0], cq[1]);
        co[1] = make_float2(cq[2], cq[3]);
        co[2] = make_float2(cq[4], cq[5]);
      }
    }
  }
}

// --- K0: standalone weight prep (kernel boundary = producer-consumer fence) -
__global__ __launch_bounds__(TPB) void prep2_kernel(const float* __restrict__ W2,
    const float* __restrict__ b2, const float* __restrict__ Wd,
    const float* __restrict__ bd, unsigned short* __restrict__ Bpack,
    float* __restrict__ Cf) {
  int idx = blockIdx.x * TPB + threadIdx.x;
  int f = idx >> 9, r = idx & 511, lane = r >> 3, j = r & 7;
  int chunk = f >> 4, ks = (f >> 2) & 3, n = f & 3;
  int k   = ks * 32 + (lane >> 4) * 8 + j;
  int col = chunk * 64 + n * 16 + (lane & 15);
  float acc = 0.f;
  for (int i = 0; i < HID; ++i)
    acc = fmaf(W2[i * HID + k], Wd[i * 256 + col], acc);
  Bpack[idx] = f2b(acc);
  if (idx < 256) {
    float c = bd[idx >> 1];
    for (int i = 0; i < HID; ++i) c = fmaf(b2[i], Wd[i * 256 + idx], c);
    Cf[idx] = c;
  }
}

// --- K1 (fused, NON-cooperative): knn -> __syncthreads -> per-block 64-row MLP
__global__ __launch_bounds__(TPB, 4) void fused_knn_mlp(
    const float* __restrict__ partial, const float* __restrict__ predicted,
    const float* __restrict__ W1, const float* __restrict__ b1,
    const float* __restrict__ Wc, const float* __restrict__ bc,
    const unsigned short* __restrict__ Bpack, const float* __restrict__ Cf,
    float* __restrict__ outp) {
  __shared__ float4 smem[Mm];                 // 32 KiB: pts, then A-tile alias
  const int tid = threadIdx.x, bid = blockIdx.x;
  const int b = bid >> 7, qt = bid & 127;
  const int lane = tid & 63, w = tid >> 6;

  float cq[6] = {0.f, 0.f, 0.f, 0.f, 0.f, 0.f};
  knn_phase(partial, predicted, smem, b, qt, tid, cq, nullptr);
  __syncthreads();                            // all pts reads done; alias LDS

  // ---- phase 2: MLP for this block's 64 rows (validated in round 11) ----
  char* Alds = (char*)smem;
  {
    const int rr = lane >> 2, q4 = lane & 3;  // 4 lanes per row
    const int srcl = (rr & 3) + ((rr >> 2) << 4);
    const float c0 = __shfl(cq[0], srcl), c1 = __shfl(cq[1], srcl),
                c2 = __shfl(cq[2], srcl), c3 = __shfl(cq[3], srcl),
                c4 = __shfl(cq[4], srcl), c5 = __shfl(cq[5], srcl);
    const int rowA = w * 16 + rr;
    const int j0 = q4 * 32;
    const float4* W1f = (const float4*)W1;
    float hbuf[32];
    #pragma unroll
    for (int jj = 0; jj < 16; ++jj) {
      float4 v0 = W1f[q4 * 48 + jj * 3 + 0];
      float4 v1 = W1f[q4 * 48 + jj * 3 + 1];
      float4 v2 = W1f[q4 * 48 + jj * 3 + 2];
      int j = j0 + jj * 2;
      float a = b1[j], e = b1[j + 1];
      a = fmaf(c0, v0.x, a); a = fmaf(c1, v0.y, a); a = fmaf(c2, v0.z, a);
      a = fmaf(c3, v0.w, a); a = fmaf(c4, v1.x, a); a = fmaf(c5, v1.y, a);
      e = fmaf(c0, v1.z, e); e = fmaf(c1, v1.w, e); e = fmaf(c2, v2.x, e);
      e = fmaf(c3, v2.y, e); e = fmaf(c4, v2.z, e); e = fmaf(c5, v2.w, e);
      hbuf[jj * 2] = fmaxf(a, 0.f); hbuf[jj * 2 + 1] = fmaxf(e, 0.f);
    }
    #pragma unroll
    for (int cc = 0; cc < 4; ++cc) {          // 4 chunks of 8 bf16, swizzled
      union { unsigned short us[8]; uint4 v; } pk;
      #pragma unroll
      for (int e2 = 0; e2 < 8; ++e2) pk.us[e2] = f2b(hbuf[cc * 8 + e2]);
      int cglob = q4 * 4 + cc;
      int byte = rowA * 256 + ((cglob * 16) ^ ((rowA & 7) << 4));
      *(uint4*)(Alds + byte) = pk.v;
    }
  }
  __syncthreads();

  const int g2 = lane >> 4, cidx = lane & 15;
  const int rA = w * 16 + cidx;
  float ac[4][3] = {};
  for (int chunk = 0; chunk < 4; ++chunk) {
    f32x4 acc[4];
    #pragma unroll
    for (int n = 0; n < 4; ++n) {
      float cfv = Cf[chunk * 64 + n * 16 + cidx];
      acc[n] = (f32x4){cfv, cfv, cfv, cfv};
    }
    #pragma unroll
    for (int ks = 0; ks < 4; ++ks) {
      short8 af = *(const short8*)(Alds + rA * 256 +
                                   ((ks * 64 + g2 * 16) ^ ((rA & 7) << 4)));
      #pragma unroll
      for (int n = 0; n < 4; ++n) {
        short8 bf = *(const short8*)((const char*)Bpack +
                     (((chunk * 4 + ks) * 4 + n) * 1024) + lane * 16);
        acc[n] = __builtin_amdgcn_mfma_f32_16x16x32_bf16(af, bf, acc[n], 0, 0, 0);
      }
    }
    #pragma unroll
    for (int n = 0; n < 4; ++n) {
      int ot = chunk * 64 + n * 16 + cidx;
      int o = ot >> 1;
      float wc0 = Wc[o], wc1 = Wc[HID + o], wc2 = Wc[2 * HID + o];
      #pragma unroll
      for (int i = 0; i < 4; ++i) {
        float v = fmaxf(acc[n][i], 0.f);
        ac[i][0] = fmaf(v, wc0, ac[i][0]);
        ac[i][1] = fmaf(v, wc1, ac[i][1]);
        ac[i][2] = fmaf(v, wc2, ac[i][2]);
      }
    }
  }

  const float bc0 = bc[0], bc1 = bc[1], bc2 = bc[2];
  const size_t rowbase = (size_t)b * Nn + qt * 64;
  #pragma unroll
  for (int i = 0; i < 4; ++i) {
    float s0 = ac[i][0], s1 = ac[i][1], s2 = ac[i][2];
    s0 += __shfl_xor(s0, 2); s0 += __shfl_xor(s0, 4); s0 += __shfl_xor(s0, 8);
    s1 += __shfl_xor(s1, 2); s1 += __shfl_xor(s1, 4); s1 += __shfl_xor(s1, 8);
    s2 += __shfl_xor(s2, 2); s2 += __shfl_xor(s2, 4); s2 += __shfl_xor(s2, 8);
    float o0 = __shfl_xor(s0, 1), o1 = __shfl_xor(s1, 1), o2 = __shfl_xor(s2, 1);
    const bool odd = lane & 1;
    float t00 = odd ? o0 : s0, t01 = odd ? o1 : s1, t02 = odd ? o2 : s2;
    float t10 = odd ? s0 : o0, t11 = odd ? s1 : o1, t12 = odd ? s2 : o2;
    if (cidx == i) {                          // writer == comb owner lane
      float* rp = outp + (rowbase + (size_t)(w * 16 + g2 * 4 + i)) * 6;
      rp[0] = cq[0] + t00 + bc0; rp[1] = cq[1] + t01 + bc1;
      rp[2] = cq[2] + t02 + bc2; rp[3] = cq[0] + t10 + bc0;
      rp[4] = cq[1] + t11 + bc1; rp[5] = cq[2] + t12 + bc2;
    }
  }
}

// --- fallback kernels (ws too small): knn-only + direct MLP -----------------
__global__ __launch_bounds__(TPB, 4) void knn_only_kernel(
    const float* __restrict__ partial, const float* __restrict__ predicted,
    float* __restrict__ outp) {
  __shared__ float4 pts[Mm];
  float cq[6];
  knn_phase(partial, predicted, pts, blockIdx.x >> 7, blockIdx.x & 127,
            threadIdx.x, cq, outp);
}

__global__ __launch_bounds__(TPB) void mlp_fallback(
    const float* __restrict__ W1, const float* __restrict__ b1,
    const float* __restrict__ W2, const float* __restrict__ b2,
    const float* __restrict__ Wd, const float* __restrict__ bd,
    const float* __restrict__ Wc, const float* __restrict__ bc,
    float* __restrict__ outp) {
  const int row = blockIdx.x * TPB + threadIdx.x;
  float2* rp = (float2*)(outp + (size_t)row * 6);
  float2 r0 = rp[0], r1 = rp[1], r2 = rp[2];
  float cc[6] = {r0.x, r0.y, r1.x, r1.y, r2.x, r2.y};
  float h[HID];
  for (int j = 0; j < HID; ++j) {
    float a = b1[j];
    for (int c = 0; c < 6; ++c) a = fmaf(cc[c], W1[j * 6 + c], a);
    h[j] = fmaxf(a, 0.f);
  }
  float sd[HID];
  for (int i = 0; i < HID; ++i) {
    float a = b2[i];
    for (int j = 0; j < HID; ++j) a = fmaf(h[j], W2[i * HID + j], a);
    sd[i] = a;
  }
  float ov[3][2] = {};
  for (int oc = 0; oc < HID; ++oc)
    for (int t = 0; t < 2; ++t) {
      float a = bd[oc];
      for (int i = 0; i < HID; ++i) a = fmaf(sd[i], Wd[i * 256 + oc * 2 + t], a);
      a = fmaxf(a, 0.f);
      for (int c = 0; c < 3; ++c) ov[c][t] = fmaf(a, Wc[c * HID + oc], ov[c][t]);
    }
  rp[0] = make_float2(cc[0] + ov[0][0] + bc[0], cc[1] + ov[1][0] + bc[1]);
  rp[1] = make_float2(cc[2] + ov[2][0] + bc[2], cc[0] + ov[0][1] + bc[0]);
  rp[2] = make_float2(cc[1] + ov[1][1] + bc[1], cc[2] + ov[2][1] + bc[2]);
}

extern "C" void kernel_launch(void* const* d_in, const int* in_sizes, int n_in,
                              void* d_out, int out_size, void* d_ws, size_t ws_size,
                              hipStream_t stream) {
  const float* partial   = (const float*)d_in[0];
  const float* predicted = (const float*)d_in[1];
  const float* W1 = (const float*)d_in[2];
  const float* b1 = (const float*)d_in[3];
  const float* W2 = (const float*)d_in[4];
  const float* b2 = (const float*)d_in[5];
  const float* Wd = (const float*)d_in[6];
  const float* bd = (const float*)d_in[7];
  const float* Wc = (const float*)d_in[8];
  const float* bc = (const float*)d_in[9];
  float* outp = (float*)d_out;

  unsigned short* Bpack = (unsigned short*)d_ws;       // 65536 B
  float* Cf = (float*)((char*)d_ws + 65536);           // 1024 B
  const bool fits = ws_size >= (size_t)66560;

  if (fits) {
    hipLaunchKernelGGL(prep2_kernel, dim3(128), dim3(TPB), 0, stream,
                       W2, b2, Wd, bd, Bpack, Cf);
    hipLaunchKernelGGL(fused_knn_mlp, dim3(KNNB), dim3(TPB), 0, stream,
                       partial, predicted, W1, b1, Wc, bc, Bpack, Cf, outp);
  } else {
    hipLaunchKernelGGL(knn_only_kernel, dim3(KNNB), dim3(TPB), 0, stream,
                       partial, predicted, outp);
    hipLaunchKernelGGL(mlp_fallback, dim3((Bb * Nn) / TPB), dim3(TPB), 0,
                       stream, W1, b1, W2, b2, Wd, bd, Wc, bc, outp);
  }
}

// Round 13
// 87.553 us; speedup vs baseline: 4.1403x; 4.1403x over previous
//
#include <hip/hip_runtime.h>
#include <hip/hip_bf16.h>
#include <math.h>

#define TPB 256
constexpr int Bb = 8, Mm = 2048, Nn = 8192, HID = 128;
constexpr int KNNB = Bb * 128;                // 1024 knn blocks
constexpr int PREPB = 128;                    // 128 fused prep blocks
constexpr int MROWS = 128;                    // rows per mlp block

typedef __attribute__((ext_vector_type(8))) short short8;
typedef __attribute__((ext_vector_type(4))) float f32x4;

__device__ __forceinline__ int vzero() { int v; asm("v_mov_b32 %0, 0" : "=v"(v)); return v; }
__device__ __forceinline__ float4 ldg4(const float* __restrict__ p, int idx4, int vz) {
  return ((const float4*)p)[idx4 + vz];
}
__device__ __forceinline__ unsigned short f2b(float x) {
  __hip_bfloat16 h = __float2bfloat16(x);
  return *reinterpret_cast<unsigned short*>(&h);
}

// in-place: a = sorted-asc top-8 of union(a,b)
__device__ __forceinline__ void mergeTop8(float a[8], const float b[8]) {
  float w[8];
  #pragma unroll
  for (int i = 0; i < 8; ++i) w[i] = fmaxf(a[i], b[7 - i]);
  #pragma unroll
  for (int i = 0; i < 4; ++i) {
    float lo = fminf(w[i], w[i + 4]); w[i + 4] = fmaxf(w[i], w[i + 4]); w[i] = lo;
  }
  #pragma unroll
  for (int g = 0; g < 8; g += 4)
    #pragma unroll
    for (int i = 0; i < 2; ++i) {
      float lo = fminf(w[g + i], w[g + i + 2]);
      w[g + i + 2] = fmaxf(w[g + i], w[g + i + 2]); w[g + i] = lo;
    }
  #pragma unroll
  for (int i = 0; i < 8; i += 2) {
    float lo = fminf(w[i], w[i + 1]); w[i + 1] = fmaxf(w[i], w[i + 1]); w[i] = lo;
  }
  #pragma unroll
  for (int i = 0; i < 8; ++i) a[i] = w[i];
}
__device__ __forceinline__ float t8of(const float a[8], const float b[8]) {
  float t = fmaxf(a[0], b[7]);
  #pragma unroll
  for (int i = 1; i < 8; ++i) t = fminf(t, fmaxf(a[i], b[7 - i]));
  return t;
}

// In-place ascending insert: step i reads only not-yet-overwritten slots.
#define INSERT8(L, u)                                                          \
  {                                                                            \
    L[0] = __builtin_amdgcn_fmed3f(u, L[0], L[1]);                             \
    L[1] = __builtin_amdgcn_fmed3f(u, L[1], L[2]);                             \
    L[2] = __builtin_amdgcn_fmed3f(u, L[2], L[3]);                             \
    L[3] = __builtin_amdgcn_fmed3f(u, L[3], L[4]);                             \
    L[4] = __builtin_amdgcn_fmed3f(u, L[4], L[5]);                             \
    L[5] = __builtin_amdgcn_fmed3f(u, L[5], L[6]);                             \
    L[6] = __builtin_amdgcn_fmed3f(u, L[6], L[7]);                             \
    L[7] = fmaxf(L[7], u);                                                     \
  }

// --- K1 (round-10 proven): blocks [0,1024) = exact 8-NN (knn6 core);
//     blocks [1024,1152) = weight prep Wf = W2^T·Wd into MFMA-B order. -------
__global__ __launch_bounds__(TPB, 4) void knn_prep_kernel(
    const float* __restrict__ partial, const float* __restrict__ predicted,
    const float* __restrict__ W2, const float* __restrict__ b2,
    const float* __restrict__ Wd, const float* __restrict__ bd,
    unsigned short* __restrict__ Bpack, float* __restrict__ Cf,
    float* __restrict__ outp) {
  __shared__ float4 pts[Mm];                  // 32 KiB {x,y,z,-0.5|p|^2}
  const int tid = threadIdx.x;

  if (blockIdx.x >= KNNB) {                   // ---- fused prep tail ----
    int idx = (blockIdx.x - KNNB) * TPB + tid;          // 0..32767
    int f = idx >> 9, r = idx & 511, lane = r >> 3, j = r & 7;
    int chunk = f >> 4, ks = (f >> 2) & 3, n = f & 3;
    int k   = ks * 32 + (lane >> 4) * 8 + j;
    int col = chunk * 64 + n * 16 + (lane & 15);
    float acc = 0.f;
    for (int i = 0; i < HID; ++i)
      acc = fmaf(W2[i * HID + k], Wd[i * 256 + col], acc);
    Bpack[idx] = f2b(acc);
    if (idx < 256) {
      float c = bd[idx >> 1];
      for (int i = 0; i < HID; ++i) c = fmaf(b2[i], Wd[i * 256 + idx], c);
      Cf[idx] = c;
    }
    return;
  }

  // ---- knn6 core ----
  const int b  = blockIdx.x >> 7;             // 1024 blocks: 8 b x 128 qt
  const int qt = blockIdx.x & 127;
  const float* pb = partial + (size_t)b * Mm * 3;
  for (int i = tid; i < Mm; i += TPB) {
    float x = pb[3 * i], y = pb[3 * i + 1], z = pb[3 * i + 2];
    pts[i] = make_float4(x, y, z, -0.5f * fmaf(x, x, fmaf(y, y, z * z)));
  }
  __syncthreads();

  const int lane = tid & 63, w = tid >> 6;
  const int s = lane & 15, g = lane >> 4;
  const int qbase = qt * 64 + w * 16 + g * 4;          // 4 consecutive queries
  const float4* qp = (const float4*)(predicted + ((size_t)b * Nn + qbase) * 3);
  const float4 qa = qp[0], qb4 = qp[1], qc = qp[2];    // 12 floats -> 4 queries
  const float q0x = qa.x,  q0y = qa.y,  q0z = qa.z;
  const float q1x = qa.w,  q1y = qb4.x, q1z = qb4.y;
  const float q2x = qb4.z, q2y = qb4.w, q2z = qc.x;
  const float q3x = qc.y,  q3y = qc.z,  q3z = qc.w;

  // pass A: per-query ascending top-8 over this lane's 128-candidate subset
  float l0[8], l1[8], l2[8], l3[8];
  #pragma unroll
  for (int i = 0; i < 8; ++i) { l0[i] = -INFINITY; l1[i] = -INFINITY;
                                l2[i] = -INFINITY; l3[i] = -INFINITY; }
  #pragma unroll 4
  for (int mm = 0; mm < 128; ++mm) {
    float4 p = pts[s + 16 * mm];              // 16 addrs/wave, 4-lane multicast
    float u0 = fmaf(q0x, p.x, fmaf(q0y, p.y, fmaf(q0z, p.z, p.w)));
    float u1 = fmaf(q1x, p.x, fmaf(q1y, p.y, fmaf(q1z, p.z, p.w)));
    float u2 = fmaf(q2x, p.x, fmaf(q2y, p.y, fmaf(q2z, p.z, p.w)));
    float u3 = fmaf(q3x, p.x, fmaf(q3y, p.y, fmaf(q3z, p.z, p.w)));
    INSERT8(l0, u0); INSERT8(l1, u1); INSERT8(l2, u2); INSERT8(l3, u3);
  }

  // merge 16 subset lists per query: full merges at d=1,2,4; t8-only at d=8
  #pragma unroll
  for (int dd = 0; dd < 3; ++dd) {
    const int d = 1 << dd;
    float ob[8];
    #pragma unroll
    for (int i = 0; i < 8; ++i) ob[i] = __shfl_xor(l0[i], d);
    mergeTop8(l0, ob);
    #pragma unroll
    for (int i = 0; i < 8; ++i) ob[i] = __shfl_xor(l1[i], d);
    mergeTop8(l1, ob);
    #pragma unroll
    for (int i = 0; i < 8; ++i) ob[i] = __shfl_xor(l2[i], d);
    mergeTop8(l2, ob);
    #pragma unroll
    for (int i = 0; i < 8; ++i) ob[i] = __shfl_xor(l3[i], d);
    mergeTop8(l3, ob);
  }
  float t80, t81, t82, t83;
  {
    float ob[8];
    #pragma unroll
    for (int i = 0; i < 8; ++i) ob[i] = __shfl_xor(l0[i], 8);
    t80 = t8of(l0, ob);
    #pragma unroll
    for (int i = 0; i < 8; ++i) ob[i] = __shfl_xor(l1[i], 8);
    t81 = t8of(l1, ob);
    #pragma unroll
    for (int i = 0; i < 8; ++i) ob[i] = __shfl_xor(l2[i], 8);
    t82 = t8of(l2, ob);
    #pragma unroll
    for (int i = 0; i < 8; ++i) ob[i] = __shfl_xor(l3[i], 8);
    t83 = t8of(l3, ob);
  }

  // pass B: accumulate u >= t8 (exactly the 8 winners unless duplicate ties)
  float a0x = 0.f, a0y = 0.f, a0z = 0.f, c0 = 0.f;
  float a1x = 0.f, a1y = 0.f, a1z = 0.f, c1 = 0.f;
  float a2x = 0.f, a2y = 0.f, a2z = 0.f, c2 = 0.f;
  float a3x = 0.f, a3y = 0.f, a3z = 0.f, c3 = 0.f;
  #pragma unroll 4
  for (int mm = 0; mm < 128; ++mm) {
    float4 p = pts[s + 16 * mm];
    float u0 = fmaf(q0x, p.x, fmaf(q0y, p.y, fmaf(q0z, p.z, p.w)));  // bitwise
    float u1 = fmaf(q1x, p.x, fmaf(q1y, p.y, fmaf(q1z, p.z, p.w)));  //  same as
    float u2 = fmaf(q2x, p.x, fmaf(q2y, p.y, fmaf(q2z, p.z, p.w)));  //  pass A
    float u3 = fmaf(q3x, p.x, fmaf(q3y, p.y, fmaf(q3z, p.z, p.w)));
    float m0 = (u0 >= t80) ? 1.f : 0.f;
    float m1 = (u1 >= t81) ? 1.f : 0.f;
    float m2 = (u2 >= t82) ? 1.f : 0.f;
    float m3 = (u3 >= t83) ? 1.f : 0.f;
    a0x = fmaf(m0, p.x, a0x); a0y = fmaf(m0, p.y, a0y); a0z = fmaf(m0, p.z, a0z); c0 += m0;
    a1x = fmaf(m1, p.x, a1x); a1y = fmaf(m1, p.y, a1y); a1z = fmaf(m1, p.z, a1z); c1 += m1;
    a2x = fmaf(m2, p.x, a2x); a2y = fmaf(m2, p.y, a2y); a2z = fmaf(m2, p.z, a2z); c2 += m2;
    a3x = fmaf(m3, p.x, a3x); a3y = fmaf(m3, p.y, a3y); a3z = fmaf(m3, p.z, a3z); c3 += m3;
  }
  // reduce across the 16 subset lanes
  #pragma unroll
  for (int dd = 0; dd < 4; ++dd) {
    const int d = 1 << dd;
    a0x += __shfl_xor(a0x, d); a0y += __shfl_xor(a0y, d); a0z += __shfl_xor(a0z, d); c0 += __shfl_xor(c0, d);
    a1x += __shfl_xor(a1x, d); a1y += __shfl_xor(a1y, d); a1z += __shfl_xor(a1z, d); c1 += __shfl_xor(c1, d);
    a2x += __shfl_xor(a2x, d); a2y += __shfl_xor(a2y, d); a2z += __shfl_xor(a2z, d); c2 += __shfl_xor(c2, d);
    a3x += __shfl_xor(a3x, d); a3y += __shfl_xor(a3y, d); a3z += __shfl_xor(a3z, d); c3 += __shfl_xor(c3, d);
  }

  // writers: lane s==k writes query qbase+k
  #pragma unroll
  for (int k = 0; k < 4; ++k) {
    if (s == k) {
      float qx = (k == 0) ? q0x : (k == 1) ? q1x : (k == 2) ? q2x : q3x;
      float qy = (k == 0) ? q0y : (k == 1) ? q1y : (k == 2) ? q2y : q3y;
      float qz = (k == 0) ? q0z : (k == 1) ? q1z : (k == 2) ? q2z : q3z;
      float t8 = (k == 0) ? t80 : (k == 1) ? t81 : (k == 2) ? t82 : t83;
      float sx = (k == 0) ? a0x : (k == 1) ? a1x : (k == 2) ? a2x : a3x;
      float sy = (k == 0) ? a0y : (k == 1) ? a1y : (k == 2) ? a2y : a3y;
      float sz = (k == 0) ? a0z : (k == 1) ? a1z : (k == 2) ? a2z : a3z;
      float cn = (k == 0) ? c0  : (k == 1) ? c1  : (k == 2) ? c2  : c3;
      if (cn != 8.0f) {                       // duplicate boundary ties: rare
        sx = sy = sz = 0.f; float cw = 0.f;
        for (int m = 0; m < Mm; ++m) {        // strict winners
          float4 p = pts[m];
          float u = fmaf(qx, p.x, fmaf(qy, p.y, fmaf(qz, p.z, p.w)));
          if (u > t8) { sx += p.x; sy += p.y; sz += p.z; cw += 1.f; }
        }
        int need = 8 - (int)cw, got = 0;
        for (int m = 0; m < Mm && got < need; ++m) {   // earliest == ties
          float4 p = pts[m];
          float u = fmaf(qx, p.x, fmaf(qy, p.y, fmaf(qz, p.z, p.w)));
          if (u == t8) { sx += p.x; sy += p.y; sz += p.z; ++got; }
        }
      }
      float2* co = (float2*)(outp + ((size_t)b * Nn + qbase + k) * 6);
      co[0] = make_float2(qx, qy);
      co[1] = make_float2(qz, sx * 0.125f);
      co[2] = make_float2(sy * 0.125f, sz * 0.125f);
    }
  }
}

// --- K2: 512 blocks x 128 rows (2 blocks/CU): fc1 (2 threads/row) -> A-LDS
//     (bf16, swizzled) -> MFMA vs Bpack (M_REP=2) -> relu+1x1conv epilogue ---
__global__ __launch_bounds__(TPB) void mlp_mfma(const float* __restrict__ W1,
    const float* __restrict__ b1, const unsigned short* __restrict__ Bpack,
    const float* __restrict__ Cf, const float* __restrict__ Wc,
    const float* __restrict__ bc, float* __restrict__ outp) {
  __shared__ char Alds[MROWS * 256];          // 32 KiB: A[128 rows][128 k] bf16
  const int tid = threadIdx.x;
  const int row0 = blockIdx.x * MROWS;
  const int vz = vzero();

  { // phase 1: fc1 + relu; 2 threads per row, each computes 64 of 128 outputs
    const int rowA = tid & 127, hf = tid >> 7;          // half: j 0..63 / 64..127
    const float* rp = outp + (size_t)(row0 + rowA) * 6;
    float2 r0 = *(const float2*)rp, r1 = *(const float2*)(rp + 2),
           r2 = *(const float2*)(rp + 4);
    const float c0 = r0.x, c1 = r0.y, c2 = r1.x, c3 = r1.y, c4 = r2.x, c5 = r2.y;
    float4 h4[16];
    #pragma unroll
    for (int jj = 0; jj < 16; ++jj) {
      const int j4 = hf * 16 + jj;            // quad of hidden units
      float4 bb = ((const float4*)b1)[j4];
      float4 w0 = ldg4(W1, j4 * 6 + 0, vz), w1 = ldg4(W1, j4 * 6 + 1, vz),
             w2 = ldg4(W1, j4 * 6 + 2, vz), w3 = ldg4(W1, j4 * 6 + 3, vz),
             w4 = ldg4(W1, j4 * 6 + 4, vz), w5 = ldg4(W1, j4 * 6 + 5, vz);
      float a0 = bb.x, a1 = bb.y, a2 = bb.z, a3 = bb.w;
      a0 = fmaf(c0, w0.x, a0); a0 = fmaf(c1, w0.y, a0); a0 = fmaf(c2, w0.z, a0);
      a0 = fmaf(c3, w0.w, a0); a0 = fmaf(c4, w1.x, a0); a0 = fmaf(c5, w1.y, a0);
      a1 = fmaf(c0, w1.z, a1); a1 = fmaf(c1, w1.w, a1); a1 = fmaf(c2, w2.x, a1);
      a1 = fmaf(c3, w2.y, a1); a1 = fmaf(c4, w2.z, a1); a1 = fmaf(c5, w2.w, a1);
      a2 = fmaf(c0, w3.x, a2); a2 = fmaf(c1, w3.y, a2); a2 = fmaf(c2, w3.z, a2);
      a2 = fmaf(c3, w3.w, a2); a2 = fmaf(c4, w4.x, a2); a2 = fmaf(c5, w4.y, a2);
      a3 = fmaf(c0, w4.z, a3); a3 = fmaf(c1, w4.w, a3); a3 = fmaf(c2, w5.x, a3);
      a3 = fmaf(c3, w5.y, a3); a3 = fmaf(c4, w5.z, a3); a3 = fmaf(c5, w5.w, a3);
      h4[jj] = make_float4(fmaxf(a0, 0.f), fmaxf(a1, 0.f), fmaxf(a2, 0.f), fmaxf(a3, 0.f));
    }
    #pragma unroll
    for (int cc = 0; cc < 8; ++cc) {          // 8 chunks of 16 B, XOR-swizzled
      float4 lo = h4[cc * 2], hi = h4[cc * 2 + 1];
      union { unsigned short us[8]; uint4 v; } pk;
      pk.us[0] = f2b(lo.x); pk.us[1] = f2b(lo.y); pk.us[2] = f2b(lo.z); pk.us[3] = f2b(lo.w);
      pk.us[4] = f2b(hi.x); pk.us[5] = f2b(hi.y); pk.us[6] = f2b(hi.z); pk.us[7] = f2b(hi.w);
      const int cglob = hf * 8 + cc;
      int byte = rowA * 256 + ((cglob * 16) ^ ((rowA & 7) << 4));
      *(uint4*)(Alds + byte) = pk.v;
    }
  }
  __syncthreads();

  // phase 2: wave computes rows [row0+wid*32, +32) x 256 cols via MFMA
  const int lane = tid & 63, wid = tid >> 6;
  const int g = lane >> 4, cidx = lane & 15;
  float ac[2][4][3] = {};

  for (int chunk = 0; chunk < 4; ++chunk) {
    f32x4 acc[2][4];
    #pragma unroll
    for (int n = 0; n < 4; ++n) {
      float cfv = Cf[chunk * 64 + n * 16 + cidx];
      #pragma unroll
      for (int m = 0; m < 2; ++m) acc[m][n] = (f32x4){cfv, cfv, cfv, cfv};
    }
    #pragma unroll
    for (int ks = 0; ks < 4; ++ks) {
      short8 af[2];
      #pragma unroll
      for (int m = 0; m < 2; ++m) {
        int r = wid * 32 + m * 16 + cidx;
        int byte = r * 256 + ((ks * 64 + g * 16) ^ ((r & 7) << 4));
        af[m] = *(const short8*)(Alds + byte);
      }
      short8 bf[4];
      #pragma unroll
      for (int n = 0; n < 4; ++n)
        bf[n] = *(const short8*)((const char*)Bpack +
                 (((chunk * 4 + ks) * 4 + n) * 1024) + lane * 16);
      #pragma unroll
      for (int m = 0; m < 2; ++m)
        #pragma unroll
        for (int n = 0; n < 4; ++n)
          acc[m][n] = __builtin_amdgcn_mfma_f32_16x16x32_bf16(af[m], bf[n], acc[m][n], 0, 0, 0);
    }
    #pragma unroll
    for (int n = 0; n < 4; ++n) {
      int ot = chunk * 64 + n * 16 + cidx;
      int o = ot >> 1;
      float wc0 = Wc[o], wc1 = Wc[HID + o], wc2 = Wc[2 * HID + o];
      #pragma unroll
      for (int m = 0; m < 2; ++m) {
        #pragma unroll
        for (int i = 0; i < 4; ++i) {
          float v = fmaxf(acc[m][n][i], 0.f);
          ac[m][i][0] = fmaf(v, wc0, ac[m][i][0]);
          ac[m][i][1] = fmaf(v, wc1, ac[m][i][1]);
          ac[m][i][2] = fmaf(v, wc2, ac[m][i][2]);
        }
      }
    }
  }

  const float bc0 = bc[0], bc1 = bc[1], bc2 = bc[2];
  #pragma unroll
  for (int m = 0; m < 2; ++m) {
    #pragma unroll
    for (int i = 0; i < 4; ++i) {
      float s0 = ac[m][i][0], s1 = ac[m][i][1], s2 = ac[m][i][2];
      s0 += __shfl_xor(s0, 2); s0 += __shfl_xor(s0, 4); s0 += __shfl_xor(s0, 8);
      s1 += __shfl_xor(s1, 2); s1 += __shfl_xor(s1, 4); s1 += __shfl_xor(s1, 8);
      s2 += __shfl_xor(s2, 2); s2 += __shfl_xor(s2, 4); s2 += __shfl_xor(s2, 8);
      float o0 = __shfl_xor(s0, 1), o1 = __shfl_xor(s1, 1), o2 = __shfl_xor(s2, 1);
      const bool odd = lane & 1;
      float t00 = odd ? o0 : s0, t01 = odd ? o1 : s1, t02 = odd ? o2 : s2;
      float t10 = odd ? s0 : o0, t11 = odd ? s1 : o1, t12 = odd ? s2 : o2;
      if (cidx == m * 4 + i) {                 // one lane per g writes its row
        int row = row0 + wid * 32 + m * 16 + g * 4 + i;
        float* rp = outp + (size_t)row * 6;
        float px = rp[0], py = rp[1], pz = rp[2];
        rp[0] = px + t00 + bc0; rp[1] = py + t01 + bc1; rp[2] = pz + t02 + bc2;
        rp[3] = px + t10 + bc0; rp[4] = py + t11 + bc1; rp[5] = pz + t12 + bc2;
      }
    }
  }
}

// --- correctness-only fallback if ws too small (no ws use) ------------------
__global__ __launch_bounds__(TPB) void mlp_fallback(
    const float* __restrict__ W1, const float* __restrict__ b1,
    const float* __restrict__ W2, const float* __restrict__ b2,
    const float* __restrict__ Wd, const float* __restrict__ bd,
    const float* __restrict__ Wc, const float* __restrict__ bc,
    float* __restrict__ outp) {
  const int row = blockIdx.x * TPB + threadIdx.x;
  float2* rp = (float2*)(outp + (size_t)row * 6);
  float2 r0 = rp[0], r1 = rp[1], r2 = rp[2];
  float cc[6] = {r0.x, r0.y, r1.x, r1.y, r2.x, r2.y};
  float h[HID];
  for (int j = 0; j < HID; ++j) {
    float a = b1[j];
    for (int c = 0; c < 6; ++c) a = fmaf(cc[c], W1[j * 6 + c], a);
    h[j] = fmaxf(a, 0.f);
  }
  float sd[HID];
  for (int i = 0; i < HID; ++i) {
    float a = b2[i];
    for (int j = 0; j < HID; ++j) a = fmaf(h[j], W2[i * HID + j], a);
    sd[i] = a;
  }
  float ov[3][2] = {};
  for (int oc = 0; oc < HID; ++oc)
    for (int t = 0; t < 2; ++t) {
      float a = bd[oc];
      for (int i = 0; i < HID; ++i) a = fmaf(sd[i], Wd[i * 256 + oc * 2 + t], a);
      a = fmaxf(a, 0.f);
      for (int c = 0; c < 3; ++c) ov[c][t] = fmaf(a, Wc[c * HID + oc], ov[c][t]);
    }
  rp[0] = make_float2(cc[0] + ov[0][0] + bc[0], cc[1] + ov[1][0] + bc[1]);
  rp[1] = make_float2(cc[2] + ov[2][0] + bc[2], cc[0] + ov[0][1] + bc[0]);
  rp[2] = make_float2(cc[1] + ov[1][1] + bc[1], cc[2] + ov[2][1] + bc[2]);
}

extern "C" void kernel_launch(void* const* d_in, const int* in_sizes, int n_in,
                              void* d_out, int out_size, void* d_ws, size_t ws_size,
                              hipStream_t stream) {
  const float* partial   = (const float*)d_in[0];
  const float* predicted = (const float*)d_in[1];
  const float* W1 = (const float*)d_in[2];
  const float* b1 = (const float*)d_in[3];
  const float* W2 = (const float*)d_in[4];
  const float* b2 = (const float*)d_in[5];
  const float* Wd = (const float*)d_in[6];
  const float* bd = (const float*)d_in[7];
  const float* Wc = (const float*)d_in[8];
  const float* bc = (const float*)d_in[9];
  float* outp = (float*)d_out;

  unsigned short* Bpack = (unsigned short*)d_ws;       // 65536 B
  float* Cf = (float*)((char*)d_ws + 65536);           // 1024 B
  const bool fits = ws_size >= (size_t)66560;

  if (fits) {
    // fused: knn blocks [0,1024) + prep blocks [1024,1152)
    hipLaunchKernelGGL(knn_prep_kernel, dim3(KNNB + PREPB), dim3(TPB), 0, stream,
                       partial, predicted, W2, b2, Wd, bd, Bpack, Cf, outp);
    hipLaunchKernelGGL(mlp_mfma, dim3((Bb * Nn) / MROWS), dim3(TPB), 0, stream,
                       W1, b1, Bpack, Cf, Wc, bc, outp);
  } else {
    // no-ws fallback: knn-only grid + direct MLP
    hipLaunchKernelGGL(knn_prep_kernel, dim3(KNNB), dim3(TPB), 0, stream,
                       partial, predicted, W2, b2, Wd, bd,
                       (unsigned short*)nullptr, (float*)nullptr, outp);
    hipLaunchKernelGGL(mlp_fallback, dim3((Bb * Nn) / TPB), dim3(TPB), 0, stream,
                       W1, b1, W2, b2, Wd, bd, Wc, bc, outp);
  }
}